// Round 3
// baseline (461.052 us; speedup 1.0000x reference)
//
#include <hip/hip_runtime.h>

// Forward-fill (LOCF) along L for x:(B,L,N) fp32, NaN = missing.
// Outputs: x_filled (B*L*N fp32) then mask as 0.0/1.0 fp32, concatenated.
//
// Two-phase chunked scan (k_carry eliminated — R1 showed its 8-block grid is a
// serial bottleneck):
//   k_tail : per (b, chunk, n) last observed value in chunk (NaN if none) -> ws
//   k_fill : each chunk-wave scans tails of preceding chunks (2-4 MiB array,
//            L2/L3-resident) to get its carry, then fills and writes out+mask.
// Streaming traffic uses nontemporal loads/stores (no reuse); tail reads stay
// cached (heavy cross-block reuse).
//
// NOTE: __builtin_nontemporal_* requires clang ext_vector_type, not the
// HIP_vector_type<float,4> wrapper (R2 compile failure).

typedef float floatx4 __attribute__((ext_vector_type(4)));

constexpr int B = 32, L = 4096, N = 256;
constexpr int N4 = N / 4;   // float4 lanes across channels (64 == one wave)
constexpr int CPB = 4;      // chunks per 256-thread block (one wave per chunk)

__device__ __forceinline__ float dev_nan() { return __int_as_float(0x7fc00000); }

// last[c] = v[c] if v[c] is observed (non-NaN) else last[c]
__device__ __forceinline__ void upd(floatx4& last, const floatx4 v) {
    last.x = (v.x == v.x) ? v.x : last.x;
    last.y = (v.y == v.y) ? v.y : last.y;
    last.z = (v.z == v.z) ? v.z : last.z;
    last.w = (v.w == v.w) ? v.w : last.w;
}

template <int LC>
__global__ __launch_bounds__(256) void k_tail(const floatx4* __restrict__ x4,
                                              floatx4* __restrict__ tail4) {
    constexpr int C = L / LC;
    const int gid   = blockIdx.x;
    const int b     = gid / (C / CPB);
    const int chunk = (gid % (C / CPB)) * CPB + (threadIdx.x >> 6);
    const int n4    = threadIdx.x & 63;

    const floatx4* p = x4 + (long)(b * L + chunk * LC) * N4 + n4;
    floatx4 last = {dev_nan(), dev_nan(), dev_nan(), dev_nan()};
#pragma unroll 8
    for (int i = 0; i < LC; ++i) {
        floatx4 v = __builtin_nontemporal_load(p + (long)i * N4);
        upd(last, v);
    }
    tail4[(long)(b * C + chunk) * N4 + n4] = last;
}

template <int LC>
__global__ __launch_bounds__(256) void k_fill(const floatx4* __restrict__ x4,
                                              const floatx4* __restrict__ tail4,
                                              floatx4* __restrict__ out4,
                                              floatx4* __restrict__ m4) {
    constexpr int C = L / LC;
    const int gid   = blockIdx.x;
    const int b     = gid / (C / CPB);
    const int chunk = (gid % (C / CPB)) * CPB + (threadIdx.x >> 6);
    const int n4    = threadIdx.x & 63;

    // Carry-in: combine tails of all preceding chunks of this series.
    // `chunk` is wave-uniform (threadIdx>>6 constant across a wave), so this
    // loop diverges only across waves. Tail array is 2-4 MiB -> cached reads.
    floatx4 last = {dev_nan(), dev_nan(), dev_nan(), dev_nan()};
    const floatx4* tb = tail4 + (long)b * C * N4 + n4;
    for (int j = 0; j < chunk; ++j) {
        upd(last, tb[(long)j * N4]);
    }

    const long base = (long)(b * L + chunk * LC) * N4 + n4;
#pragma unroll 4
    for (int i = 0; i < LC; ++i) {
        const long idx = base + (long)i * N4;
        floatx4 v = __builtin_nontemporal_load(x4 + idx);
        const bool ox = (v.x == v.x);
        const bool oy = (v.y == v.y);
        const bool oz = (v.z == v.z);
        const bool ow = (v.w == v.w);
        upd(last, v);
        floatx4 o;
        o.x = (last.x == last.x) ? last.x : 0.0f;
        o.y = (last.y == last.y) ? last.y : 0.0f;
        o.z = (last.z == last.z) ? last.z : 0.0f;
        o.w = (last.w == last.w) ? last.w : 0.0f;
        __builtin_nontemporal_store(o, out4 + idx);
        if (m4) {
            floatx4 m = {ox ? 1.0f : 0.0f, oy ? 1.0f : 0.0f,
                         oz ? 1.0f : 0.0f, ow ? 1.0f : 0.0f};
            __builtin_nontemporal_store(m, m4 + idx);
        }
    }
}

template <int LC>
static void run_all(const float* x, float* out, float* mask_out, void* d_ws,
                    hipStream_t stream) {
    constexpr int C = L / LC;
    float* tail = (float*)d_ws;
    k_tail<LC><<<B * C / CPB, 256, 0, stream>>>((const floatx4*)x, (floatx4*)tail);
    k_fill<LC><<<B * C / CPB, 256, 0, stream>>>((const floatx4*)x,
                                                (const floatx4*)tail,
                                                (floatx4*)out, (floatx4*)mask_out);
}

extern "C" void kernel_launch(void* const* d_in, const int* in_sizes, int n_in,
                              void* d_out, int out_size, void* d_ws, size_t ws_size,
                              hipStream_t stream) {
    const float* x = (const float*)d_in[0];
    const long n_total = (long)B * L * N;  // 33,554,432

    float* out = (float*)d_out;
    float* mask_out = ((long)out_size >= 2 * n_total) ? out + n_total : nullptr;

    // LC=32 (C=128): 4 MiB tail scratch, 1024-block grids (16 waves/CU).
    // Fallback LC=128 (C=32): 1 MiB scratch.
    if (ws_size >= (size_t)B * (L / 32) * N * sizeof(float)) {
        run_all<32>(x, out, mask_out, d_ws, stream);
    } else {
        run_all<128>(x, out, mask_out, d_ws, stream);
    }
}

// Round 4
// 436.838 us; speedup vs baseline: 1.0554x; 1.0554x over previous
//
#include <hip/hip_runtime.h>

// Forward-fill (LOCF) along L for x:(B,L,N) fp32, NaN = missing.
// Outputs: x_filled (B*L*N fp32) then mask as 0.0/1.0 fp32, concatenated.
//
// Two-phase chunked scan:
//   k_tail : per (b, chunk, n) last observed value in chunk (NaN if none) -> ws
//            x read with REGULAR loads (warms L3; x = 134 MB < 256 MiB L3).
//   k_fill : each chunk-wave combines tails of preceding chunks (4 MiB array,
//            L2/L3-resident) for its carry, then fills. x re-read hits L3.
//            out/mask stores are nontemporal (pure streaming, no reuse).
//
// R3 lesson: nt loads on x prevented L3 allocation -> k_fill re-read x from
// HBM (+40 us). nt belongs on the store streams only.
// R2 lesson: __builtin_nontemporal_* requires clang ext_vector_type.

typedef float floatx4 __attribute__((ext_vector_type(4)));

constexpr int B = 32, L = 4096, N = 256;
constexpr int N4 = N / 4;   // float4 lanes across channels (64 == one wave)
constexpr int CPB = 4;      // chunks per 256-thread block (one wave per chunk)

__device__ __forceinline__ float dev_nan() { return __int_as_float(0x7fc00000); }

// last[c] = v[c] if v[c] is observed (non-NaN) else last[c]
__device__ __forceinline__ void upd(floatx4& last, const floatx4 v) {
    last.x = (v.x == v.x) ? v.x : last.x;
    last.y = (v.y == v.y) ? v.y : last.y;
    last.z = (v.z == v.z) ? v.z : last.z;
    last.w = (v.w == v.w) ? v.w : last.w;
}

template <int LC>
__global__ __launch_bounds__(256) void k_tail(const floatx4* __restrict__ x4,
                                              floatx4* __restrict__ tail4) {
    constexpr int C = L / LC;
    const int gid   = blockIdx.x;
    const int b     = gid / (C / CPB);
    const int chunk = (gid % (C / CPB)) * CPB + (threadIdx.x >> 6);
    const int n4    = threadIdx.x & 63;

    const floatx4* p = x4 + (long)(b * L + chunk * LC) * N4 + n4;
    floatx4 last = {dev_nan(), dev_nan(), dev_nan(), dev_nan()};
#pragma unroll 8
    for (int i = 0; i < LC; ++i) {
        floatx4 v = p[(long)i * N4];   // caching load: warm L3 for k_fill
        upd(last, v);
    }
    tail4[(long)(b * C + chunk) * N4 + n4] = last;
}

template <int LC>
__global__ __launch_bounds__(256) void k_fill(const floatx4* __restrict__ x4,
                                              const floatx4* __restrict__ tail4,
                                              floatx4* __restrict__ out4,
                                              floatx4* __restrict__ m4) {
    constexpr int C = L / LC;
    const int gid   = blockIdx.x;
    const int b     = gid / (C / CPB);
    const int chunk = (gid % (C / CPB)) * CPB + (threadIdx.x >> 6);
    const int n4    = threadIdx.x & 63;

    // Carry-in: combine tails of all preceding chunks of this series.
    // `chunk` is wave-uniform, so this loop diverges only across waves.
    floatx4 last = {dev_nan(), dev_nan(), dev_nan(), dev_nan()};
    const floatx4* tb = tail4 + (long)b * C * N4 + n4;
    for (int j = 0; j < chunk; ++j) {
        upd(last, tb[(long)j * N4]);
    }

    const long base = (long)(b * L + chunk * LC) * N4 + n4;
#pragma unroll 4
    for (int i = 0; i < LC; ++i) {
        const long idx = base + (long)i * N4;
        floatx4 v = x4[idx];           // caching load: should hit L3
        const bool ox = (v.x == v.x);
        const bool oy = (v.y == v.y);
        const bool oz = (v.z == v.z);
        const bool ow = (v.w == v.w);
        upd(last, v);
        floatx4 o;
        o.x = (last.x == last.x) ? last.x : 0.0f;
        o.y = (last.y == last.y) ? last.y : 0.0f;
        o.z = (last.z == last.z) ? last.z : 0.0f;
        o.w = (last.w == last.w) ? last.w : 0.0f;
        __builtin_nontemporal_store(o, out4 + idx);
        if (m4) {
            floatx4 m = {ox ? 1.0f : 0.0f, oy ? 1.0f : 0.0f,
                         oz ? 1.0f : 0.0f, ow ? 1.0f : 0.0f};
            __builtin_nontemporal_store(m, m4 + idx);
        }
    }
}

template <int LC>
static void run_all(const float* x, float* out, float* mask_out, void* d_ws,
                    hipStream_t stream) {
    constexpr int C = L / LC;
    float* tail = (float*)d_ws;
    k_tail<LC><<<B * C / CPB, 256, 0, stream>>>((const floatx4*)x, (floatx4*)tail);
    k_fill<LC><<<B * C / CPB, 256, 0, stream>>>((const floatx4*)x,
                                                (const floatx4*)tail,
                                                (floatx4*)out, (floatx4*)mask_out);
}

extern "C" void kernel_launch(void* const* d_in, const int* in_sizes, int n_in,
                              void* d_out, int out_size, void* d_ws, size_t ws_size,
                              hipStream_t stream) {
    const float* x = (const float*)d_in[0];
    const long n_total = (long)B * L * N;  // 33,554,432

    float* out = (float*)d_out;
    float* mask_out = ((long)out_size >= 2 * n_total) ? out + n_total : nullptr;

    // LC=32 (C=128): 4 MiB tail scratch, 1024-block grids (16 waves/CU).
    // Fallback LC=128 (C=32): 1 MiB scratch.
    if (ws_size >= (size_t)B * (L / 32) * N * sizeof(float)) {
        run_all<32>(x, out, mask_out, d_ws, stream);
    } else {
        run_all<128>(x, out, mask_out, d_ws, stream);
    }
}